// Round 4
// baseline (215.762 us; speedup 1.0000x reference)
//
#include <hip/hip_runtime.h>

#define BATCH 64
#define T 480000
#define T4 (T / 4)                     // 120000 float4 chunks per row
#define NTAPS 16
#define TILE 512                       // output chunks per tile
#define TPR ((T4 + TILE - 1) / TILE)   // 235 tiles per row (last: 192 valid chunks)
#define NTILES (BATCH * TPR)           // 15040 tiles
#define LDSC 576                       // LDS slots per buffer (516 used)
#define GRID 2048                      // persistent: 8 blocks/CU, ~7.3 tiles/block

typedef float floatx4 __attribute__((ext_vector_type(4)));

// Stage one tile (slots 0..515 = row chunks t*TILE-4 .. t*TILE+511, edge-clamped)
// straight into LDS. Wave w issues segs {w, w+4}; wave 0 also the 4-chunk seg 8.
// Per-wave vmcnt contribution: wave 0 = 3 loads, waves 1-3 = 2 loads.
__device__ __forceinline__ void stage_tile(const float* __restrict__ x,
                                           int g, floatx4* ldsbuf,
                                           int lane, int wave)
{
    const int r      = g / TPR;
    const int t      = g - r * TPR;
    const int base_c = t * TILE - 4;
    const float* xrow = x + (size_t)r * T;

#pragma unroll
    for (int s = 0; s < 2; ++s) {
        const int seg = wave + 4 * s;
        int c = base_c + seg * 64 + lane;
        c = c < 0 ? 0 : c;
        c = c > T4 - 1 ? T4 - 1 : c;
        const float* gp = xrow + (size_t)c * 4;
        __builtin_amdgcn_global_load_lds(
            (const __attribute__((address_space(1))) void*)gp,
            (__attribute__((address_space(3))) void*)((char*)ldsbuf + seg * 1024),
            16, 0, 0);
    }
    if (wave == 0 && lane < 4) {       // partial seg 8: slots 512..515 only
        int c = base_c + 512 + lane;
        c = c < 0 ? 0 : c;
        c = c > T4 - 1 ? T4 - 1 : c;
        const float* gp = xrow + (size_t)c * 4;
        __builtin_amdgcn_global_load_lds(
            (const __attribute__((address_space(1))) void*)gp,
            (__attribute__((address_space(3))) void*)((char*)ldsbuf + 512 * 16),
            16, 0, 0);
    }
}

__device__ __forceinline__ void compute_tile(int g, const floatx4* __restrict__ ldsbuf,
                                             const float* __restrict__ tap,
                                             floatx4* __restrict__ y4, int tid)
{
    const int r = g / TPR;
    const int t = g - r * TPR;
    floatx4* yv = y4 + (size_t)r * T4;

#pragma unroll
    for (int p = 0; p < 2; ++p) {
        const int j = tid + 256 * p;   // output chunk within tile; needs slots j..j+4

        float s[20];
#pragma unroll
        for (int m = 0; m < 5; ++m) {  // 5x ds_read_b128, lane stride 16 B
            floatx4 v = ldsbuf[j + m];
            s[4 * m + 0] = v.x;
            s[4 * m + 1] = v.y;
            s[4 * m + 2] = v.z;
            s[4 * m + 3] = v.w;
        }

        if (t == 0) {                  // row start: x[t<0] = 0 (slots 0..3 hold clamp garbage)
#pragma unroll
            for (int m = 0; m < 5; ++m)
                if (j + m < 4) { s[4*m] = 0.f; s[4*m+1] = 0.f; s[4*m+2] = 0.f; s[4*m+3] = 0.f; }
        }

        floatx4 out;
#pragma unroll
        for (int q = 0; q < 4; ++q) {
            float a = 0.f;
#pragma unroll
            for (int k = 0; k < NTAPS; ++k) a += tap[k] * s[16 + q - k];
            out[q] = a;
        }

        const int oc = t * TILE + j;
        if (oc < T4) yv[oc] = out;     // coalesced full-line store
    }
}

__global__ __launch_bounds__(256) void fir_pipe_kernel(
    const float* __restrict__ x,
    const float* __restrict__ b,
    float* __restrict__ y)
{
    // Double-buffered LDS: 2 x 9216 B -> still 8 blocks/CU, 32 waves/CU.
    // Counted vmcnt keeps next tile's loads in flight ACROSS the barrier ->
    // per-CU read stream never drains (T3/T4 pattern at the memory roofline).
    __shared__ floatx4 lds4[2][LDSC];

    const int tid  = threadIdx.x;
    const int lane = tid & 63;
    const int wave = tid >> 6;

    float tap[NTAPS];                  // wave-uniform addr + literal idx -> SGPRs
#pragma unroll
    for (int k = 0; k < NTAPS; ++k) tap[k] = b[k];

    floatx4* y4 = (floatx4*)y;

    int g = blockIdx.x;
    stage_tile(x, g, lds4[0], lane, wave);
    asm volatile("s_waitcnt vmcnt(0)" ::: "memory");   // prologue: drain own stage

    int cur = 0;
    for (; g < NTILES; g += GRID) {
        const int gn = g + GRID;
        if (gn < NTILES) {
            stage_tile(x, gn, lds4[cur ^ 1], lane, wave);
            // Per-wave queue oldest->newest: [stage_cur][stores 0..2][stage_next].
            // Wait until exactly |stage_next| remain: drains stage_cur (and the
            // old stores) for EVERY wave, including waves whose stores were
            // predicated off, while keeping stage_next fully in flight.
            if (wave == 0) asm volatile("s_waitcnt vmcnt(3)" ::: "memory");
            else           asm volatile("s_waitcnt vmcnt(2)" ::: "memory");
        } else {
            asm volatile("s_waitcnt vmcnt(0)" ::: "memory");   // tail: drain all
        }
        __builtin_amdgcn_s_barrier();          // all waves' stage_cur landed
        compute_tile(g, lds4[cur], tap, y4, tid);
        __builtin_amdgcn_s_barrier();          // all done reading buf cur
        cur ^= 1;                              // (it's re-staged next iteration)
    }
}

extern "C" void kernel_launch(void* const* d_in, const int* in_sizes, int n_in,
                              void* d_out, int out_size, void* d_ws, size_t ws_size,
                              hipStream_t stream)
{
    const float* x = (const float*)d_in[0];
    const float* b = (const float*)d_in[1];
    float* y = (float*)d_out;

    fir_pipe_kernel<<<GRID, 256, 0, stream>>>(x, b, y);
}

// Round 5
// 206.205 us; speedup vs baseline: 1.0463x; 1.0463x over previous
//
#include <hip/hip_runtime.h>

#define BATCH 64
#define T 480000
#define T4 (T / 4)              // 120000 float4 chunks per row
#define NTAPS 16
#define NC (BATCH * T4)         // 7,680,000 chunks = 30000 blocks x 256 threads exactly

typedef float floatx4 __attribute__((ext_vector_type(4)));

// Minimal comparator kernel: one thread = one output chunk, one-shot grid.
// 5 clamped dwordx4 loads (lanes overlap -> 4/5 are L1 hits), 64 FMAs, 1 store.
// No loop, no LDS, no barriers, no pipeline registers: nothing here can bind
// below the memory system. This measures the machine's mixed R/W rate for this
// footprint while still producing the exact FIR output.
__global__ __launch_bounds__(256) void fir_min_kernel(
    const float* __restrict__ x,
    const float* __restrict__ b,
    float* __restrict__ y)
{
    const int idx = blockIdx.x * 256 + threadIdx.x;     // < NC by construction

    // Taps: wave-uniform address + literal indices -> s_load_dwordx4, SGPRs.
    float tap[NTAPS];
#pragma unroll
    for (int k = 0; k < NTAPS; ++k) tap[k] = b[k];

    const unsigned row  = (unsigned)idx / (unsigned)T4; // magic-mul div
    const int      col4 = idx - (int)(row * T4);
    const floatx4* xr   = (const floatx4*)(x + (size_t)row * T);

    // Own chunk + 4 halo chunks (branchless clamp; t<0 -> zeros, row start only).
    float s[20];
#pragma unroll
    for (int m = 0; m < 5; ++m) {
        const int c  = col4 - 4 + m;
        const int cc = c < 0 ? 0 : c;
        floatx4 t = xr[cc];
        if (c < 0) t = (floatx4){0.f, 0.f, 0.f, 0.f};
        s[4 * m + 0] = t.x;
        s[4 * m + 1] = t.y;
        s[4 * m + 2] = t.z;
        s[4 * m + 3] = t.w;
    }

    floatx4 out;
#pragma unroll
    for (int j = 0; j < 4; ++j) {
        float a = 0.f;
#pragma unroll
        for (int k = 0; k < NTAPS; ++k) a += tap[k] * s[16 + j - k];
        out[j] = a;
    }

    ((floatx4*)y)[idx] = out;   // coalesced full-line store (nt was A/B'd: neutral)
}

extern "C" void kernel_launch(void* const* d_in, const int* in_sizes, int n_in,
                              void* d_out, int out_size, void* d_ws, size_t ws_size,
                              hipStream_t stream)
{
    const float* x = (const float*)d_in[0];
    const float* b = (const float*)d_in[1];
    float* y = (float*)d_out;

    fir_min_kernel<<<NC / 256, 256, 0, stream>>>(x, b, y);
}